// Round 3
// baseline (117.138 us; speedup 1.0000x reference)
//
#include <hip/hip_runtime.h>

constexpr int DSZ = 192, HSZ = 192, WSZ = 192, BSZ = 2;
constexpr int WQ   = WSZ / 4;        // 48 float4 per row
constexpr int SEG  = 6;              // rows per thread (rolling window)
constexpr int NSEG = HSZ / SEG;      // 32 segments per column
constexpr int TPB  = 256;
constexpr int NBLOCKS = (BSZ * DSZ * NSEG * WQ) / TPB;  // 2304, %8==0
constexpr int HW = HSZ * WSZ;
constexpr float SMOOTH = 1e-5f;

__device__ __forceinline__ float4 ld4(const float* __restrict__ p) {
    return *reinterpret_cast<const float4*>(p);
}

// 4-wide gradient magnitude from rolling rows + d-neighbors + w-edge scalars
__device__ __forceinline__ void mag4(float4 c, float4 hp, float4 hn,
                                     float4 d0, float4 d1, float wl, float wr,
                                     float o[4]) {
    float gx0 = d1.x - d0.x, gx1 = d1.y - d0.y, gx2 = d1.z - d0.z, gx3 = d1.w - d0.w;
    float gy0 = hn.x - hp.x, gy1 = hn.y - hp.y, gy2 = hn.z - hp.z, gy3 = hn.w - hp.w;
    float gz0 = c.y - wl,    gz1 = c.z - c.x,   gz2 = c.w - c.y,   gz3 = wr - c.z;
    o[0] = sqrtf(fmaf(gx0, gx0, fmaf(gy0, gy0, fmaf(gz0, gz0, SMOOTH))));
    o[1] = sqrtf(fmaf(gx1, gx1, fmaf(gy1, gy1, fmaf(gz1, gz1, SMOOTH))));
    o[2] = sqrtf(fmaf(gx2, gx2, fmaf(gy2, gy2, fmaf(gz2, gz2, SMOOTH))));
    o[3] = sqrtf(fmaf(gx3, gx3, fmaf(gy3, gy3, fmaf(gz3, gz3, SMOOTH))));
}

__global__ __launch_bounds__(TPB, 4)
void bl_main(const float* __restrict__ pred,
             const float* __restrict__ target,
             double* __restrict__ acc) {
    // XCD-chunked swizzle: each XCD gets a contiguous 288-block (48-plane) slab
    const int swz = (blockIdx.x & 7) * (NBLOCKS / 8) + (blockIdx.x >> 3);
    const int gid = swz * TPB + threadIdx.x;
    const int wq  = gid % WQ;
    const int t   = gid / WQ;
    const int seg = t % NSEG;
    const int bd  = t / NSEG;          // b*DSZ + d
    const int d   = bd % DSZ;
    const int h0  = seg * SEG;

    const float4 z = make_float4(0.f, 0.f, 0.f, 0.f);
    const float* __restrict__ P = pred   + (size_t)bd * HW + wq * 4;
    const float* __restrict__ T = target + (size_t)bd * HW + wq * 4;

    float4 pPrev = (h0 > 0) ? ld4(P + (h0 - 1) * WSZ) : z;
    float4 tPrev = (h0 > 0) ? ld4(T + (h0 - 1) * WSZ) : z;
    float4 pCur  = ld4(P + h0 * WSZ);
    float4 tCur  = ld4(T + h0 * WSZ);

    float s_pt = 0.f, s_p = 0.f, s_t = 0.f;

    #pragma unroll
    for (int s = 0; s < SEG; ++s) {
        const int h = h0 + s;
        const float* Pr = P + h * WSZ;
        const float* Tr = T + h * WSZ;

        float4 pNext = (h < HSZ - 1) ? ld4(Pr + WSZ) : z;
        float4 tNext = (h < HSZ - 1) ? ld4(Tr + WSZ) : z;
        float4 pd0   = (d > 0)       ? ld4(Pr - HW)  : z;
        float4 td0   = (d > 0)       ? ld4(Tr - HW)  : z;
        float4 pd1   = (d < DSZ - 1) ? ld4(Pr + HW)  : z;
        float4 td1   = (d < DSZ - 1) ? ld4(Tr + HW)  : z;
        float pwl = (wq > 0)      ? Pr[-1] : 0.f;
        float twl = (wq > 0)      ? Tr[-1] : 0.f;
        float pwr = (wq < WQ - 1) ? Pr[4]  : 0.f;
        float twr = (wq < WQ - 1) ? Tr[4]  : 0.f;

        float pb[4], tb[4];
        mag4(pCur, pPrev, pNext, pd0, pd1, pwl, pwr, pb);
        mag4(tCur, tPrev, tNext, td0, td1, twl, twr, tb);

        #pragma unroll
        for (int j = 0; j < 4; ++j) {
            s_pt = fmaf(pb[j], tb[j], s_pt);
            s_p += pb[j];
            s_t += tb[j];
        }

        pPrev = pCur; pCur = pNext;
        tPrev = tCur; tCur = tNext;
    }

    // 64-lane wave reduction
    #pragma unroll
    for (int off = 32; off; off >>= 1) {
        s_pt += __shfl_down(s_pt, off);
        s_p  += __shfl_down(s_p,  off);
        s_t  += __shfl_down(s_t,  off);
    }

    __shared__ float red[4][4];   // 4 waves x {pt,p,t}
    const int lane = threadIdx.x & 63;
    const int wid  = threadIdx.x >> 6;
    if (lane == 0) {
        red[wid][0] = s_pt;
        red[wid][1] = s_p;
        red[wid][2] = s_t;
    }
    __syncthreads();
    if (threadIdx.x == 0) {
        double a_pt = 0.0, a_p = 0.0, a_t = 0.0;
        #pragma unroll
        for (int k = 0; k < 4; ++k) {
            a_pt += (double)red[k][0];
            a_p  += (double)red[k][1];
            a_t  += (double)red[k][2];
        }
        atomicAdd(&acc[0],  a_pt);
        atomicAdd(&acc[8],  a_p);
        atomicAdd(&acc[16], a_t);
    }
}

__global__ void bl_final(const double* __restrict__ acc, float* __restrict__ out) {
    const double I = acc[0];
    const double Pm = acc[8];
    const double Tm = acc[16];
    const double dice = (2.0 * I + 1e-5) / (Pm + Tm + 1e-5);
    out[0] = (float)(1.0 - dice);
}

extern "C" void kernel_launch(void* const* d_in, const int* in_sizes, int n_in,
                              void* d_out, int out_size, void* d_ws, size_t ws_size,
                              hipStream_t stream) {
    const float* pred   = (const float*)d_in[0];
    const float* target = (const float*)d_in[1];
    double* acc = (double*)d_ws;

    hipMemsetAsync(d_ws, 0, 17 * sizeof(double), stream);
    bl_main<<<NBLOCKS, TPB, 0, stream>>>(pred, target, acc);
    bl_final<<<1, 1, 0, stream>>>(acc, (float*)d_out);
}

// Round 4
// 62.575 us; speedup vs baseline: 1.8720x; 1.8720x over previous
//
#include <hip/hip_runtime.h>

constexpr int DSZ = 192, HSZ = 192, WSZ = 192, BSZ = 2;
constexpr int WQ = WSZ / 4;                  // 48 float4 per row
constexpr int HP = HSZ / 2;                  // 96 row-pairs per plane
constexpr int TPB = 256;
constexpr int ITERS = 3;
constexpr int NPAIR = BSZ * DSZ * HP * WQ;   // 1,769,472 pair-tasks
constexpr int NBLOCKS = NPAIR / (TPB * ITERS);  // 2304, %8==0
constexpr int HW = HSZ * WSZ;
constexpr float SMOOTH = 1e-5f;

__device__ __forceinline__ float4 ld4(const float* __restrict__ p) {
    return *reinterpret_cast<const float4*>(p);
}

// 4-wide boundary magnitude: center row c, rows above/below hm/hn,
// planes d0/d1, scalar w-edges wl/wr
__device__ __forceinline__ void mag4(float4 c, float4 hm, float4 hn,
                                     float4 d0, float4 d1, float wl, float wr,
                                     float o[4]) {
    float gx0 = d1.x - d0.x, gx1 = d1.y - d0.y, gx2 = d1.z - d0.z, gx3 = d1.w - d0.w;
    float gy0 = hn.x - hm.x, gy1 = hn.y - hm.y, gy2 = hn.z - hm.z, gy3 = hn.w - hm.w;
    float gz0 = c.y - wl,    gz1 = c.z - c.x,   gz2 = c.w - c.y,   gz3 = wr - c.z;
    o[0] = sqrtf(fmaf(gx0, gx0, fmaf(gy0, gy0, fmaf(gz0, gz0, SMOOTH))));
    o[1] = sqrtf(fmaf(gx1, gx1, fmaf(gy1, gy1, fmaf(gz1, gz1, SMOOTH))));
    o[2] = sqrtf(fmaf(gx2, gx2, fmaf(gy2, gy2, fmaf(gz2, gz2, SMOOTH))));
    o[3] = sqrtf(fmaf(gx3, gx3, fmaf(gy3, gy3, fmaf(gz3, gz3, SMOOTH))));
}

// load the 8-voxel pair-task stencil for one array and produce two mag4s
__device__ __forceinline__ void pair_mags(const float* __restrict__ X,
                                          int d, int hp, int wq,
                                          float m0[4], float m1[4]) {
    const float4 z = make_float4(0.f, 0.f, 0.f, 0.f);
    float4 rm = (hp > 0 || true) ? ((2 * hp > 0) ? ld4(X - WSZ) : z) : z;
    float4 r0 = ld4(X);
    float4 r1 = ld4(X + WSZ);
    float4 r2 = (hp < HP - 1) ? ld4(X + 2 * WSZ) : z;
    float4 d0a = (d > 0)       ? ld4(X - HW)        : z;
    float4 d0b = (d > 0)       ? ld4(X - HW + WSZ)  : z;
    float4 d1a = (d < DSZ - 1) ? ld4(X + HW)        : z;
    float4 d1b = (d < DSZ - 1) ? ld4(X + HW + WSZ)  : z;
    float wl0 = (wq > 0)      ? X[-1]        : 0.f;
    float wr0 = (wq < WQ - 1) ? X[4]         : 0.f;
    float wl1 = (wq > 0)      ? X[WSZ - 1]   : 0.f;
    float wr1 = (wq < WQ - 1) ? X[WSZ + 4]   : 0.f;
    mag4(r0, rm, r1, d0a, d1a, wl0, wr0, m0);   // row h
    mag4(r1, r0, r2, d0b, d1b, wl1, wr1, m1);   // row h+1
}

__global__ __launch_bounds__(TPB)
void bl_main(const float* __restrict__ pred,
             const float* __restrict__ target,
             double* __restrict__ acc) {
    // XCD-chunked swizzle: each XCD gets a contiguous slab of blocks
    const int swz = (blockIdx.x & 7) * (NBLOCKS / 8) + (blockIdx.x >> 3);
    const int pid_base = swz * (TPB * ITERS) + threadIdx.x;

    float s_pt = 0.f, s_p = 0.f, s_t = 0.f;

    #pragma unroll 1
    for (int i = 0; i < ITERS; ++i) {
        const int pid = pid_base + i * TPB;
        const int wq  = pid % WQ;
        const int rp  = pid / WQ;
        const int hp  = rp % HP;
        const int bd  = rp / HP;
        const int d   = bd % DSZ;
        const size_t off = (size_t)bd * HW + (size_t)(2 * hp) * WSZ + wq * 4;

        float pb0[4], pb1[4], tb0[4], tb1[4];
        pair_mags(pred + off,   d, hp, wq, pb0, pb1);
        pair_mags(target + off, d, hp, wq, tb0, tb1);

        #pragma unroll
        for (int j = 0; j < 4; ++j) {
            s_pt = fmaf(pb0[j], tb0[j], s_pt);
            s_pt = fmaf(pb1[j], tb1[j], s_pt);
            s_p += pb0[j] + pb1[j];
            s_t += tb0[j] + tb1[j];
        }
    }

    // 64-lane wave reduction
    #pragma unroll
    for (int off = 32; off; off >>= 1) {
        s_pt += __shfl_down(s_pt, off);
        s_p  += __shfl_down(s_p,  off);
        s_t  += __shfl_down(s_t,  off);
    }

    __shared__ float red[4][4];   // 4 waves x {pt,p,t}
    const int lane = threadIdx.x & 63;
    const int wid  = threadIdx.x >> 6;
    if (lane == 0) {
        red[wid][0] = s_pt;
        red[wid][1] = s_p;
        red[wid][2] = s_t;
    }
    __syncthreads();
    if (threadIdx.x == 0) {
        double a_pt = 0.0, a_p = 0.0, a_t = 0.0;
        #pragma unroll
        for (int k = 0; k < 4; ++k) {
            a_pt += (double)red[k][0];
            a_p  += (double)red[k][1];
            a_t  += (double)red[k][2];
        }
        atomicAdd(&acc[0],  a_pt);
        atomicAdd(&acc[8],  a_p);
        atomicAdd(&acc[16], a_t);
    }
}

__global__ void bl_final(const double* __restrict__ acc, float* __restrict__ out) {
    const double I = acc[0];
    const double Pm = acc[8];
    const double Tm = acc[16];
    const double dice = (2.0 * I + 1e-5) / (Pm + Tm + 1e-5);
    out[0] = (float)(1.0 - dice);
}

extern "C" void kernel_launch(void* const* d_in, const int* in_sizes, int n_in,
                              void* d_out, int out_size, void* d_ws, size_t ws_size,
                              hipStream_t stream) {
    const float* pred   = (const float*)d_in[0];
    const float* target = (const float*)d_in[1];
    double* acc = (double*)d_ws;

    hipMemsetAsync(d_ws, 0, 17 * sizeof(double), stream);
    bl_main<<<NBLOCKS, TPB, 0, stream>>>(pred, target, acc);
    bl_final<<<1, 1, 0, stream>>>(acc, (float*)d_out);
}